// Round 2
// baseline (252.838 us; speedup 1.0000x reference)
//
#include <hip/hip_runtime.h>
#include <hip/hip_cooperative_groups.h>
#include <math.h>

namespace cg = cooperative_groups;

// Problem constants (fixed by the reference)
#define BD   128      // batch == hidden
#define ID   1024     // img dim
#define TD   1024     // txt dim
#define NE   32768    // edges
#define HD   128      // hidden

// ---------------------------------------------------------------------------
// Single fused cooperative kernel, 512 blocks x 256 threads (2 blocks/CU).
//
// Phase A: HimgT[i,h] = sum_b img[b,i]*W1[h,b]        (+ b1[h] folded in)
//          HtxtT[t,h] = sum_b text[b,t]*W1[h,128+b]
//   512 blocks x 4 feature-rows each. The 4-column input tile is staged
//   through LDS (the "transpose"); W1 rows are walked sequentially per
//   thread -> ~8 KB hot lines per block, L1-resident. LDS reads in the
//   b-loop are wave-broadcast (all lanes same address).
//
// Phase B: a[e] = sigmoid(w2 . relu(HimgT[src]+HtxtT[tgt]) + b2)
//   2048 waves x 16 edges each; 64 lanes cover 128 h (2/lane), shfl-reduce.
//
// Phase C: batch-major scatter (NO CSR, NO transposes needed):
//   attended_img[b,i]  = sum_{e:src=i} a[e]*text[b,tgt[e]]
//   attended_text[b,t] = sum_{e:tgt=t} a[e]*img[b,src[e]]
//   task = (side, b, half-of-edges): stage feature row (4 KB) + acc (4 KB)
//   in LDS, LDS-float-atomicAdd per edge, flush with coalesced global
//   atomicAdd into pre-zeroed d_out (2-way contention only).
// ---------------------------------------------------------------------------
__global__ __launch_bounds__(256, 2) void fused_kernel(
    const float* __restrict__ img, const float* __restrict__ text,
    const int* __restrict__ src, const int* __restrict__ tgt,
    const float* __restrict__ W1, const float* __restrict__ b1,
    const float* __restrict__ w2, const float* __restrict__ b2,
    float* __restrict__ HimgT, float* __restrict__ HtxtT,
    float* __restrict__ a_e, float* __restrict__ out)
{
    __shared__ float lds[2048];   // 8 KB, reused across phases
    cg::grid_group grid = cg::this_grid();
    const int blk = blockIdx.x;   // 0..511
    const int tid = threadIdx.x;  // 0..255

    // ---------------- Phase A: H precompute ----------------
    {
        const int sideA = blk >> 8;          // 0: img, 1: txt (256 blocks each)
        const int i0 = (blk & 255) * 4;      // 4 feature-rows per block
        const float* S  = sideA ? text : img;
        float* Dst      = sideA ? HtxtT : HimgT;

        // stage S[b][il] (b 0..127, il 0..3) into lds[b*4+il]
        #pragma unroll
        for (int r = 0; r < 2; r++) {
            int idx = r * 256 + tid;
            int b = idx >> 2, il = idx & 3;
            lds[idx] = S[b * 1024 + i0 + il];
        }
        __syncthreads();

        const int h = tid & 127, iq = tid >> 7;
        const int il0 = iq * 2, il1 = il0 + 1;
        const float* wrow = W1 + h * 256 + (sideA ? 128 : 0); // L1-hot walk
        float acc0 = 0.f, acc1 = 0.f;
        #pragma unroll 4
        for (int b = 0; b < 128; b++) {
            float w = wrow[b];
            acc0 += lds[b * 4 + il0] * w;   // LDS broadcast
            acc1 += lds[b * 4 + il1] * w;
        }
        const float bias = sideA ? 0.f : b1[h];   // fold b1 into img side
        Dst[(i0 + il0) * 128 + h] = acc0 + bias;
        Dst[(i0 + il1) * 128 + h] = acc1 + bias;
    }

    grid.sync();

    // ---------------- Phase B: per-edge attention scalar ----------------
    {
        const int lane = tid & 63;
        const int wv = tid >> 6;                 // wave 0..3
        const int wgid = blk * 4 + wv;           // 0..2047
        const float w2a = w2[lane], w2b = w2[lane + 64];
        const float b2v = b2[0];
        #pragma unroll 2
        for (int k = 0; k < 16; k++) {
            int e = wgid * 16 + k;
            int s0 = src[e], t0 = tgt[e];
            const float* Hi = HimgT + s0 * 128;
            const float* Ht = HtxtT + t0 * 128;
            float v1 = Hi[lane]      + Ht[lane];
            float v2 = Hi[lane + 64] + Ht[lane + 64];
            float x = fmaxf(v1, 0.f) * w2a + fmaxf(v2, 0.f) * w2b;
            #pragma unroll
            for (int off = 32; off > 0; off >>= 1)
                x += __shfl_xor(x, off, 64);
            if (lane == 0)
                a_e[e] = 1.f / (1.f + expf(-(x + b2v)));
        }
    }

    grid.sync();

    // ---------------- Phase C: batch-major scatter ----------------
    {
        const int sideC = blk >> 8;        // 0: attended_img, 1: attended_text
        const int b     = (blk & 255) >> 1;// batch row 0..127
        const int chunk = blk & 1;         // which half of the edges
        const float* Row = (sideC ? img : text) + b * 1024;
        float* acc  = lds;                 // [1024]
        float* rowl = lds + 1024;          // [1024]

        #pragma unroll
        for (int k = 0; k < 4; k++) {
            int idx = k * 256 + tid;
            rowl[idx] = Row[idx];          // coalesced 4 KB stage
            acc[idx]  = 0.f;
        }
        __syncthreads();

        const int e0 = chunk * 16384;
        #pragma unroll 2
        for (int k = 0; k < 64; k++) {
            int e = e0 + k * 256 + tid;
            int s0 = src[e], t0 = tgt[e];
            float av = a_e[e];
            if (sideC == 0)
                atomicAdd(&acc[s0], av * rowl[t0]);  // LDS float atomic
            else
                atomicAdd(&acc[t0], av * rowl[s0]);
        }
        __syncthreads();

        float* obase = out + sideC * (BD * ID) + b * 1024;
        #pragma unroll
        for (int k = 0; k < 4; k++) {
            int idx = k * 256 + tid;
            atomicAdd(&obase[idx], acc[idx]);        // coalesced, 2-way
        }
    }
}

extern "C" void kernel_launch(void* const* d_in, const int* in_sizes, int n_in,
                              void* d_out, int out_size, void* d_ws, size_t ws_size,
                              hipStream_t stream)
{
    const float* img  = (const float*)d_in[0];   // [128,1024]
    const float* text = (const float*)d_in[1];   // [128,1024]
    const int*   src  = (const int*)  d_in[2];   // [32768]
    const int*   tgt  = (const int*)  d_in[3];   // [32768]
    const float* W1   = (const float*)d_in[4];   // [128,256]
    const float* b1   = (const float*)d_in[5];   // [128]
    const float* w2   = (const float*)d_in[6];   // [128]
    const float* b2   = (const float*)d_in[7];   // [1]
    float* out = (float*)d_out;                  // 2 x [128,1024] concat

    // workspace: 1.18 MB
    float* HimgT = (float*)d_ws;         // 131072 floats (b1 folded in)
    float* HtxtT = HimgT + 131072;       // 131072
    float* a_e   = HtxtT + 131072;       // 32768

    // Phase C accumulates into out with atomics -> zero it first
    hipMemsetAsync(out, 0, (size_t)out_size * sizeof(float), stream);

    void* args[] = { (void*)&img, (void*)&text, (void*)&src, (void*)&tgt,
                     (void*)&W1, (void*)&b1, (void*)&w2, (void*)&b2,
                     (void*)&HimgT, (void*)&HtxtT, (void*)&a_e, (void*)&out };
    hipLaunchCooperativeKernel((void*)fused_kernel, dim3(512), dim3(256),
                               args, 0, stream);
}

// Round 3
// 126.042 us; speedup vs baseline: 2.0060x; 2.0060x over previous
//
#include <hip/hip_runtime.h>
#include <math.h>

// Problem constants (fixed by the reference)
#define BD   128      // batch == hidden
#define ID   1024     // img dim
#define TD   1024     // txt dim
#define NE   32768    // edges
#define HD   128      // hidden

// ---------------------------------------------------------------------------
// K_A: H precompute. 256 blocks x 256 threads, 8 feature-rows per block.
//   HimgT[i,h] = sum_b img[b,i]*W1[h,b]       (+ b1[h] folded in)
//   HtxtT[t,h] = sum_b text[b,t]*W1[h,128+b]
// W1-side is staged TRANSPOSED into LDS in two 64-b halves (stride 129 ->
// conflict-free both on write and read); S-tile staged via float4.
// Inner loop per b: 1 ds_read_b32 (W, conflict-free across h-lanes) +
// 1 ds_read_b128 (S, wave-broadcast) + 4 FMA.
// ---------------------------------------------------------------------------
__global__ __launch_bounds__(256) void h_kernel(
    const float* __restrict__ img, const float* __restrict__ text,
    const float* __restrict__ W1, const float* __restrict__ b1,
    float* __restrict__ HimgT, float* __restrict__ HtxtT)
{
    __shared__ __align__(16) float Wl[64 * 129];  // 33 KB: Wl[b'*129+h]
    __shared__ __align__(16) float Sl[128 * 8];   // 4 KB:  Sl[b*8+il]
    const int blk = blockIdx.x, tid = threadIdx.x;
    const int side = blk >> 7;            // 0: img, 1: txt (128 blocks each)
    const int i0 = (blk & 127) * 8;
    const float* S = side ? text : img;
    float* Dst = side ? HtxtT : HimgT;
    const int soff = side * 128;

    // stage S tile: 128 rows x 8 floats = 256 float4, one per thread (coalesced)
    {
        int b = tid >> 1, q = tid & 1;
        ((float4*)Sl)[tid] = *(const float4*)(S + b * 1024 + i0 + q * 4);
    }

    const int h = tid & 127, iq = tid >> 7;
    float acc[4] = {0.f, 0.f, 0.f, 0.f};
    #pragma unroll
    for (int half = 0; half < 2; half++) {
        __syncthreads();   // Sl ready (1st) / Wl no longer read (2nd)
        // stage W half transposed: coalesced global (64-float row segments),
        // stride-129 LDS writes (conflict-free)
        for (int idx = tid; idx < 8192; idx += 256) {
            int hh = idx >> 6, bb = idx & 63;
            Wl[bb * 129 + hh] = W1[hh * 256 + soff + half * 64 + bb];
        }
        __syncthreads();
        #pragma unroll 8
        for (int bb = 0; bb < 64; bb++) {
            int b = half * 64 + bb;
            float w = Wl[bb * 129 + h];                       // conflict-free
            float4 s4 = *(const float4*)(Sl + b * 8 + iq * 4); // broadcast
            acc[0] += s4.x * w; acc[1] += s4.y * w;
            acc[2] += s4.z * w; acc[3] += s4.w * w;
        }
    }
    float bias = side ? 0.f : b1[h];      // fold b1 into img side
    #pragma unroll
    for (int r = 0; r < 4; r++)
        Dst[(i0 + iq * 4 + r) * 128 + h] = acc[r] + bias;   // coalesced
}

// ---------------------------------------------------------------------------
// K_B: a[e] = sigmoid(w2 . relu(HimgT[src]+HtxtT[tgt]) + b2)
// 2048 blocks x 256 thr = 8192 waves (8/SIMD), 4 edges per wave.
// 64 lanes cover 128 h (2/lane), shfl-xor reduce.
// ---------------------------------------------------------------------------
__global__ __launch_bounds__(256) void edge_kernel(
    const int* __restrict__ src, const int* __restrict__ tgt,
    const float* __restrict__ HimgT, const float* __restrict__ HtxtT,
    const float* __restrict__ w2, const float* __restrict__ b2,
    float* __restrict__ a_e)
{
    const int lane = threadIdx.x & 63;
    const int wgid = blockIdx.x * 4 + (threadIdx.x >> 6);   // 0..8191
    const float w2a = w2[lane], w2b = w2[lane + 64];
    const float b2v = b2[0];
    #pragma unroll
    for (int k = 0; k < 4; k++) {
        int e = wgid * 4 + k;
        int s0 = src[e], t0 = tgt[e];
        const float* Hi = HimgT + s0 * 128;
        const float* Ht = HtxtT + t0 * 128;
        float v1 = Hi[lane]      + Ht[lane];
        float v2 = Hi[lane + 64] + Ht[lane + 64];
        float x = fmaxf(v1, 0.f) * w2a + fmaxf(v2, 0.f) * w2b;
        #pragma unroll
        for (int off = 32; off > 0; off >>= 1)
            x += __shfl_xor(x, off, 64);
        if (lane == 0)
            a_e[e] = 1.f / (1.f + expf(-(x + b2v)));
    }
}

// ---------------------------------------------------------------------------
// K_C: batch-major scatter, one block per (side, batch-row), ALL 32768 edges:
//   attended_img[b,i]  = sum_{e:src=i} a[e]*text[b,tgt[e]]
//   attended_text[b,t] = sum_{e:tgt=t} a[e]*img[b,src[e]]
// Feature row (4 KB) + accumulator (4 KB) in LDS; int4/float4 edge loads
// (L2-hot); LDS float atomics; flush is a PLAIN coalesced store covering
// every output element -> no memset of d_out needed.
// ---------------------------------------------------------------------------
__global__ __launch_bounds__(256) void scatter_kernel(
    const int* __restrict__ src, const int* __restrict__ tgt,
    const float* __restrict__ a_e,
    const float* __restrict__ img, const float* __restrict__ text,
    float* __restrict__ out)
{
    __shared__ float acc[1024];
    __shared__ float rowl[1024];
    const int blk = blockIdx.x, tid = threadIdx.x;
    const int side = blk >> 7, b = blk & 127;   // 256 blocks total
    const float* Row = (side ? img : text) + b * 1024;
    #pragma unroll
    for (int k = 0; k < 4; k++) {
        int idx = k * 256 + tid;
        rowl[idx] = Row[idx];     // coalesced 4 KB stage
        acc[idx]  = 0.f;
    }
    __syncthreads();
    const int4*   s4 = (const int4*)src;
    const int4*   t4 = (const int4*)tgt;
    const float4* a4 = (const float4*)a_e;
    #pragma unroll 2
    for (int k = 0; k < 32; k++) {
        int idx = k * 256 + tid;             // covers 32768 edges as int4
        int4 ss = s4[idx]; int4 tt = t4[idx]; float4 aa = a4[idx];
        if (side == 0) {
            atomicAdd(&acc[ss.x], aa.x * rowl[tt.x]);
            atomicAdd(&acc[ss.y], aa.y * rowl[tt.y]);
            atomicAdd(&acc[ss.z], aa.z * rowl[tt.z]);
            atomicAdd(&acc[ss.w], aa.w * rowl[tt.w]);
        } else {
            atomicAdd(&acc[tt.x], aa.x * rowl[ss.x]);
            atomicAdd(&acc[tt.y], aa.y * rowl[ss.y]);
            atomicAdd(&acc[tt.z], aa.z * rowl[ss.z]);
            atomicAdd(&acc[tt.w], aa.w * rowl[ss.w]);
        }
    }
    __syncthreads();
    float* obase = out + side * (BD * ID) + b * 1024;
    #pragma unroll
    for (int k = 0; k < 4; k++) {
        int idx = k * 256 + tid;
        obase[idx] = acc[idx];    // plain coalesced store, every elem written
    }
}

extern "C" void kernel_launch(void* const* d_in, const int* in_sizes, int n_in,
                              void* d_out, int out_size, void* d_ws, size_t ws_size,
                              hipStream_t stream)
{
    const float* img  = (const float*)d_in[0];   // [128,1024]
    const float* text = (const float*)d_in[1];   // [128,1024]
    const int*   src  = (const int*)  d_in[2];   // [32768]
    const int*   tgt  = (const int*)  d_in[3];   // [32768]
    const float* W1   = (const float*)d_in[4];   // [128,256]
    const float* b1   = (const float*)d_in[5];   // [128]
    const float* w2   = (const float*)d_in[6];   // [128]
    const float* b2   = (const float*)d_in[7];   // [1]
    float* out = (float*)d_out;                  // 2 x [128,1024] concat

    // workspace: 1.18 MB
    float* HimgT = (float*)d_ws;         // 131072 floats (b1 folded in)
    float* HtxtT = HimgT + 131072;       // 131072
    float* a_e   = HtxtT + 131072;       // 32768

    h_kernel<<<256, 256, 0, stream>>>(img, text, W1, b1, HimgT, HtxtT);
    edge_kernel<<<2048, 256, 0, stream>>>(src, tgt, HimgT, HtxtT, w2, b2, a_e);
    scatter_kernel<<<256, 256, 0, stream>>>(src, tgt, a_e, img, text, out);
}